// Round 16
// baseline (756.231 us; speedup 1.0000x reference)
//
#include <hip/hip_runtime.h>
#include <hip/hip_cooperative_groups.h>

namespace cg = cooperative_groups;

#define NEG 0.01f
#define HF 128   // hidden features
#define BK 64    // bucket slots per node (Poisson(16): P(deg>64) ~ e^-45)
#define PB 512   // partition blocks (segments per bin)
#define SEG 40   // slots per (block,bin) cell; lambda~8 -> P(X>=40) ~ 1e-17

typedef __attribute__((ext_vector_type(8))) short bf8;   // 8 bf16 (4 VGPRs)
typedef __attribute__((ext_vector_type(4))) float f4;
typedef __attribute__((ext_vector_type(2))) float f2;

__device__ __forceinline__ unsigned short f2bf(float v) {
    unsigned u = __float_as_uint(v);
    u = (u + 0x7fff + ((u >> 16) & 1)) >> 16;   // round-to-nearest-even
    return (unsigned short)u;
}

// ---------------- mega1: {edge partition} ⊕ {embedding GEMM} ⊕ {wt_c prep} ⊕ {BN const prep} ----------------
// bins: 256-node windows (bin = dst>>8); requires N <= 65536 (also for src<<8 packing and ushort buckets).
__global__ __launch_bounds__(256) void k_mega1(
        const int* __restrict__ src, const int* __restrict__ dst, int E,
        int* __restrict__ cellcnt, int* __restrict__ binbuf,
        const float* __restrict__ x, const float* __restrict__ W_emb,
        const float* __restrict__ b_emb, short* __restrict__ hbuf, int N,
        const float* __restrict__ convW, short* __restrict__ wt_c, int L,
        const float* __restrict__ convB,
        const float* __restrict__ bn_g, const float* __restrict__ bn_b,
        const float* __restrict__ bn_m, const float* __restrict__ bn_v,
        float* __restrict__ scb, float* __restrict__ shb,
        int NBIN, int EB, int WB) {
    __shared__ short wt[128 * 88];           // emb: padded W_emb^T (bank-conflict-free)
    __shared__ int lcur[256];
    const int bid = blockIdx.x;
    const int tid = threadIdx.x;

    if (bid < PB) {
        lcur[tid] = 0;
        __syncthreads();
        const int per = (E + PB - 1) / PB;
        const int e0 = bid * per;
        const int e1 = (e0 + per < E) ? e0 + per : E;
        for (int e = e0 + tid; e < e1; e += 256) {
            const int d = dst[e];
            const int b = d >> 8;
            const int p = atomicAdd(&lcur[b], 1);
            if (p < SEG)
                binbuf[((size_t)b * PB + bid) * SEG + p] = (src[e] << 8) | (d & 255);
        }
        __syncthreads();
        if (tid < NBIN) {
            int c = lcur[tid];
            cellcnt[(size_t)tid * PB + bid] = c < SEG ? c : SEG;
        }
        return;
    }
    if (bid < PB + EB) {
        for (int i = tid; i < 128 * 64; i += 256) {
            const int n = i >> 6, k = i & 63;
            wt[n * 88 + k] = (short)f2bf(W_emb[(size_t)k * HF + n]);
        }
        __syncthreads();
        const int wid = tid >> 6, lane = tid & 63;
        const int lr = lane & 15, lk = lane >> 4;
        const int m0 = (bid - PB) * 64 + wid * 16;
        if (m0 >= N) return;
        const int arow_i = m0 + lr < N ? m0 + lr : N - 1;
        bf8 a[2];
        const float* arow = x + (size_t)arow_i * 64 + lk * 8;
#pragma unroll
        for (int kk = 0; kk < 2; ++kk) {
            const float4 p = *reinterpret_cast<const float4*>(arow + kk * 32);
            const float4 q = *reinterpret_cast<const float4*>(arow + kk * 32 + 4);
            bf8 t;
            t[0] = (short)f2bf(p.x); t[1] = (short)f2bf(p.y);
            t[2] = (short)f2bf(p.z); t[3] = (short)f2bf(p.w);
            t[4] = (short)f2bf(q.x); t[5] = (short)f2bf(q.y);
            t[6] = (short)f2bf(q.z); t[7] = (short)f2bf(q.w);
            a[kk] = t;
        }
#pragma unroll
        for (int n = 0; n < 8; ++n) {
            f4 acc = {0.f, 0.f, 0.f, 0.f};
            const short* brow = wt + (n * 16 + lr) * 88 + lk * 8;
#pragma unroll
            for (int kk = 0; kk < 2; ++kk) {
                const bf8 b = *reinterpret_cast<const bf8*>(brow + kk * 32);
                acc = __builtin_amdgcn_mfma_f32_16x16x32_bf16(a[kk], b, acc, 0, 0, 0);
            }
            const int col = n * 16 + lr;
            const float bs = b_emb[col];
#pragma unroll
            for (int r = 0; r < 4; ++r)
                hbuf[(size_t)(m0 + lk * 4 + r) * HF + col] = (short)f2bf(acc[r] + bs);
        }
        return;
    }
    if (bid < PB + EB + WB) {
        const int i = (bid - PB - EB) * 256 + tid;
        const int per = HF * HF;
        if (i < L * per) {
            const int l = i / per, r = i % per;
            const int n = r / HF, k = r % HF;
            wt_c[i] = (short)f2bf(convW[(size_t)l * per + (size_t)k * HF + n]);
        }
        return;
    }
    const int i = (bid - PB - EB - WB) * 256 + tid;
    if (i < L * HF) {
        const float s = rsqrtf(bn_v[i] + 1e-5f) * bn_g[i];
        scb[i] = s;
        shb[i] = (convB[i] - bn_m[i]) * s + bn_b[i];
    }
}

// ================= fused cooperative kernel: binfill -> L x (gemm, gather) -> pool -> mlp =================
__global__ __launch_bounds__(256, 4) void k_fused(
        const int* __restrict__ cellcnt, const int* __restrict__ binbuf,
        unsigned short* __restrict__ bkt, int* __restrict__ cnt,
        float* __restrict__ gbuf, short* __restrict__ mzero,
        int NBIN, int ZRIDX,
        short* __restrict__ hbuf, short* __restrict__ ms,
        const short* __restrict__ wt_c,
        const float* __restrict__ scb, const float* __restrict__ shb,
        int L, int N,
        const int* __restrict__ batch,
        const float* __restrict__ W1, const float* __restrict__ b1,
        const float* __restrict__ W2, const float* __restrict__ b2,
        float* __restrict__ out) {
    cg::grid_group grid = cg::this_grid();
    __shared__ int lcnt[256];
    __shared__ float gr[128];
    __shared__ float z[64];
    const int tid = threadIdx.x;
    const int gdim = gridDim.x;
    const int wid4 = tid >> 6, lane = tid & 63;

    // ---- phase 0: binfill (L2-local bucket scatter, ushort indices) + gbuf/zero-row init ----
    for (int bid = blockIdx.x; bid <= NBIN; bid += gdim) {
        if (bid == NBIN) {
            for (int i = tid; i < 64 * HF; i += 256) gbuf[i] = 0.0f;
            if (tid < 64) reinterpret_cast<int*>(mzero)[tid] = 0;
            continue;
        }
        lcnt[tid] = 0;
        __syncthreads();
        for (int sg = tid; sg < PB; sg += 256) {
            const int c = cellcnt[(size_t)bid * PB + sg];
            const int* segp = binbuf + ((size_t)bid * PB + sg) * SEG;
            for (int i = 0; i < c; ++i) {
                const int ed = segp[i];
                const int dl = ed & 255;
                const int p = atomicAdd(&lcnt[dl], 1);
                if (p < BK)
                    bkt[(size_t)((bid << 8) + dl) * BK + p] =
                        (unsigned short)((unsigned)ed >> 8);
            }
        }
        __syncthreads();
        int c = lcnt[tid];
        if (c > BK) c = BK;
        const int pc = (c + 7) & ~7;
        const int node = (bid << 8) + tid;
        unsigned short* brow = bkt + (size_t)node * BK;
        for (int p = c; p < pc; ++p) brow[p] = (unsigned short)ZRIDX;
        cnt[node] = c;
        __syncthreads();
    }
    grid.sync();

    // ---- conv layers ----
    const int lr = lane & 15, lk = lane >> 4;
    for (int l = 0; l < L; ++l) {
        // gemm phase: ms = dinv * (hbuf @ Wl), 32 rows/wave
        const short* Bt = wt_c + (size_t)l * HF * HF;
        const int T = (N + 127) >> 7;
        for (int bid = blockIdx.x; bid < T; bid += gdim) {
            const int m0 = bid * 128 + wid4 * 32;
            if (m0 >= N) continue;
            bf8 aA[4], aB[4];
            const short* arowA = hbuf + (size_t)(m0 + lr) * HF + lk * 8;
            const short* arowB = arowA + 16 * HF;
#pragma unroll
            for (int kk = 0; kk < 4; ++kk) {
                aA[kk] = *reinterpret_cast<const bf8*>(arowA + kk * 32);
                aB[kk] = *reinterpret_cast<const bf8*>(arowB + kk * 32);
            }
            float dvA[4], dvB[4];
#pragma unroll
            for (int r = 0; r < 4; ++r) {
                int rowA = m0 + lk * 4 + r;       if (rowA >= N) rowA = N - 1;
                int rowB = m0 + 16 + lk * 4 + r;  if (rowB >= N) rowB = N - 1;
                dvA[r] = rsqrtf((float)cnt[rowA] + 1.0f);
                dvB[r] = rsqrtf((float)cnt[rowB] + 1.0f);
            }
#pragma unroll
            for (int n = 0; n < 8; ++n) {
                f4 accA = {0.f, 0.f, 0.f, 0.f};
                f4 accB = {0.f, 0.f, 0.f, 0.f};
                const short* brow = Bt + (size_t)(n * 16 + lr) * HF + lk * 8;
#pragma unroll
                for (int kk = 0; kk < 4; ++kk) {
                    const bf8 b = *reinterpret_cast<const bf8*>(brow + kk * 32);
                    accA = __builtin_amdgcn_mfma_f32_16x16x32_bf16(aA[kk], b, accA, 0, 0, 0);
                    accB = __builtin_amdgcn_mfma_f32_16x16x32_bf16(aB[kk], b, accB, 0, 0, 0);
                }
                const int col = n * 16 + lr;
#pragma unroll
                for (int r = 0; r < 4; ++r) {
                    ms[(size_t)(m0 + lk * 4 + r) * HF + col]      = (short)f2bf(accA[r] * dvA[r]);
                    ms[(size_t)(m0 + 16 + lk * 4 + r) * HF + col] = (short)f2bf(accB[r] * dvB[r]);
                }
            }
        }
        grid.sync();

        // gather phase: hbuf = LReLU(BN(dinv*(gather+self)))
        const float* sc = scb + l * HF;
        const float* sh = shb + l * HF;
        const int sub = lane >> 4;
        const int lf  = lane & 15;
        for (int base = blockIdx.x * 4; base < N; base += gdim * 4) {
            const int node = base + wid4;
            if (node >= N) continue;
            const size_t b0 = (size_t)node * BK;
            const int myoff = ((int)bkt[b0 + lane]) << 8;
            const int deg = cnt[node];
            const int pdeg = (deg + 7) & ~7;

            f2 acc[4];
#pragma unroll
            for (int j = 0; j < 4; ++j) acc[j] = (f2){0.f, 0.f};
            union U { bf8 v; unsigned u[4]; };

            U self;
            self.v = *reinterpret_cast<const bf8*>(ms + (size_t)node * HF + lf * 8);

            const char* msb = (const char*)ms + lf * 16;
            for (int t = sub; t < pdeg; t += 8) {
                const int o0 = __shfl(myoff, t);
                const int o1 = __shfl(myoff, t + 4);
                U a, b;
                a.v = *reinterpret_cast<const bf8*>(msb + o0);
                b.v = *reinterpret_cast<const bf8*>(msb + o1);
#pragma unroll
                for (int j = 0; j < 4; ++j) {
                    f2 va, vb;
                    va.x = __uint_as_float(a.u[j] << 16);
                    va.y = __uint_as_float(a.u[j] & 0xffff0000u);
                    vb.x = __uint_as_float(b.u[j] << 16);
                    vb.y = __uint_as_float(b.u[j] & 0xffff0000u);
                    acc[j] += va + vb;
                }
            }
            if (sub == 0) {
#pragma unroll
                for (int j = 0; j < 4; ++j) {
                    f2 val;
                    val.x = __uint_as_float(self.u[j] << 16);
                    val.y = __uint_as_float(self.u[j] & 0xffff0000u);
                    acc[j] += val;
                }
            }
#pragma unroll
            for (int j = 0; j < 4; ++j) {
                acc[j].x += __shfl_xor(acc[j].x, 16);
                acc[j].y += __shfl_xor(acc[j].y, 16);
                acc[j].x += __shfl_xor(acc[j].x, 32);
                acc[j].y += __shfl_xor(acc[j].y, 32);
            }
            if (sub == 0) {
                const float dv = rsqrtf((float)deg + 1.0f);
                const int f0 = lf * 8;
                const float4 sca = *reinterpret_cast<const float4*>(sc + f0);
                const float4 scb2 = *reinterpret_cast<const float4*>(sc + f0 + 4);
                const float4 sha = *reinterpret_cast<const float4*>(sh + f0);
                const float4 shb2 = *reinterpret_cast<const float4*>(sh + f0 + 4);
                const float scv[8] = {sca.x, sca.y, sca.z, sca.w, scb2.x, scb2.y, scb2.z, scb2.w};
                const float shv[8] = {sha.x, sha.y, sha.z, sha.w, shb2.x, shb2.y, shb2.z, shb2.w};
                unsigned ou[4];
#pragma unroll
                for (int j = 0; j < 4; ++j) {
                    float vx = fmaf(acc[j].x * dv, scv[2 * j],     shv[2 * j]);
                    float vy = fmaf(acc[j].y * dv, scv[2 * j + 1], shv[2 * j + 1]);
                    vx = fmaxf(vx, NEG * vx);
                    vy = fmaxf(vy, NEG * vy);
                    ou[j] = (unsigned)f2bf(vx) | ((unsigned)f2bf(vy) << 16);
                }
                *reinterpret_cast<uint4*>(hbuf + (size_t)node * HF + f0) =
                    *reinterpret_cast<uint4*>(ou);
            }
        }
        grid.sync();
    }

    // ---- pool phase: wave-parallel segmented accumulation ----
    {
        const int totw = gdim * 4;
        const int per = (N + totw - 1) / totw;
        const int gwid = blockIdx.x * 4 + wid4;
        const int n0 = gwid * per;
        if (n0 < N) {
            const int n1 = (n0 + per < N) ? n0 + per : N;
            const int fp = lane * 2;
            float ax = 0.f, ay = 0.f;
            int cur = batch[n0];
            for (int n = n0; n < n1; ++n) {
                const int b = batch[n];
                if (b != cur) {
                    atomicAdd(&gbuf[cur * HF + fp], ax);
                    atomicAdd(&gbuf[cur * HF + fp + 1], ay);
                    ax = 0.f; ay = 0.f; cur = b;
                }
                const unsigned u = *reinterpret_cast<const unsigned*>(hbuf + (size_t)n * HF + fp);
                ax += __uint_as_float(u << 16);
                ay += __uint_as_float(u & 0xffff0000u);
            }
            atomicAdd(&gbuf[cur * HF + fp], ax);
            atomicAdd(&gbuf[cur * HF + fp + 1], ay);
        }
    }
    grid.sync();

    // ---- mlp phase: blocks 0..63, one graph each ----
    if (blockIdx.x < 64) {
        const int gid = blockIdx.x;
        if (tid < 128) gr[tid] = gbuf[gid * HF + tid];
        __syncthreads();
        if (tid < 64) {
            float acc = b1[tid];
#pragma unroll 8
            for (int k = 0; k < 128; ++k) acc += gr[k] * W1[k * 64 + tid];
            z[tid] = acc > 0.0f ? acc : NEG * acc;
        }
        __syncthreads();
        if (tid < 8) {
            float acc = b2[tid];
#pragma unroll 8
            for (int j = 0; j < 64; ++j) acc += z[j] * W2[j * 8 + tid];
            out[gid * 8 + tid] = acc;
        }
    }
}

extern "C" void kernel_launch(void* const* d_in, const int* in_sizes, int n_in,
                              void* d_out, int out_size, void* d_ws, size_t ws_size,
                              hipStream_t stream) {
    const float* x       = (const float*)d_in[0];
    const int*   eidx    = (const int*)  d_in[1];
    const int*   batch   = (const int*)  d_in[2];
    const float* W_emb   = (const float*)d_in[3];
    const float* b_emb   = (const float*)d_in[4];
    const float* convW   = (const float*)d_in[5];
    const float* convB   = (const float*)d_in[6];
    const float* bn_g    = (const float*)d_in[7];
    const float* bn_b    = (const float*)d_in[8];
    const float* bn_m    = (const float*)d_in[9];
    const float* bn_v    = (const float*)d_in[10];
    const float* W1      = (const float*)d_in[11];
    const float* b1      = (const float*)d_in[12];
    const float* W2      = (const float*)d_in[13];
    const float* b2      = (const float*)d_in[14];

    const int F_IN = 64;
    const int N = in_sizes[0] / F_IN;
    const int E = in_sizes[1] / 2;
    const int L = in_sizes[5] / (HF * HF);
    const int G = 64;

    const int* esrc = eidx;
    const int* edst = eidx + E;

    const int NBIN  = (N + 255) >> 8;            // 256-node windows (requires N <= 65536)
    const int Npad2 = NBIN << 8;                 // bucket/cnt row count
    const int Npad  = ((N + 127) / 128) * 128;

    // workspace layout (16B alignment maintained)
    unsigned short* bkt = (unsigned short*)d_ws;             // Npad2*BK ushort
    int* cnt      = (int*)(bkt + (size_t)Npad2 * BK);        // Npad2
    int* cellcnt  = cnt + Npad2;                             // NBIN*PB
    int* binbuf   = cellcnt + (size_t)NBIN * PB;             // NBIN*PB*SEG ints (packed)
    short* hbuf   = (short*)(binbuf + (size_t)NBIN * PB * SEG); // Npad*HF bf16
    short* ms     = hbuf + (size_t)Npad * HF;                // (Npad+128)*HF bf16 (+zero row)
    short* wt_c   = ms + (size_t)(Npad + 128) * HF;          // L*128*128 bf16
    float* gbuf   = (float*)(wt_c + (size_t)L * HF * HF);    // G*HF fp32
    float* scb    = gbuf + G * HF;                           // L*HF
    float* shb    = scb + L * HF;                            // L*HF
    short* mzero  = ms + (size_t)Npad * HF;

    // 1. mega1: edge partition ⊕ embedding GEMM ⊕ wt_c prep ⊕ BN const prep
    const int EB = (N + 63) / 64;
    const int WB = (L * HF * HF + 255) / 256;
    const int SB = (L * HF + 255) / 256;
    k_mega1<<<PB + EB + WB + SB, 256, 0, stream>>>(
        esrc, edst, E, cellcnt, binbuf, x, W_emb, b_emb, hbuf, N,
        convW, wt_c, L, convB, bn_g, bn_b, bn_m, bn_v, scb, shb,
        NBIN, EB, WB);

    // 2. fused cooperative kernel: binfill -> L x (gemm, gather) -> pool -> mlp
    int gdim = 1024;                              // 4 blocks/CU target
    {
        int maxb = 0;
        if (hipOccupancyMaxActiveBlocksPerMultiprocessor(
                &maxb, (const void*)k_fused, 256, 0) == hipSuccess && maxb > 0) {
            const int cap = maxb * 256;           // 256 CUs
            if (cap < gdim) gdim = cap;
        } else {
            gdim = 512;                           // conservative fallback
        }
    }
    int NBINv = NBIN, ZRIDXv = Npad, Lv = L, Nv = N;
    float* outp = (float*)d_out;
    void* kargs[] = {
        (void*)&cellcnt, (void*)&binbuf, (void*)&bkt, (void*)&cnt,
        (void*)&gbuf, (void*)&mzero, (void*)&NBINv, (void*)&ZRIDXv,
        (void*)&hbuf, (void*)&ms, (void*)&wt_c,
        (void*)&scb, (void*)&shb, (void*)&Lv, (void*)&Nv,
        (void*)&batch, (void*)&W1, (void*)&b1, (void*)&W2, (void*)&b2,
        (void*)&outp};
    hipLaunchCooperativeKernel((void*)k_fused, dim3(gdim), dim3(256), kargs, 0, stream);
}

// Round 17
// 203.631 us; speedup vs baseline: 3.7137x; 3.7137x over previous
//
#include <hip/hip_runtime.h>

#define NEG 0.01f
#define HF 128   // hidden features
#define BK 64    // bucket slots per node (Poisson(16): P(deg>64) ~ e^-45)
#define PB 512   // partition blocks (segments per bin)
#define SEG 40   // slots per (block,bin) cell; lambda~8 -> P(X>=40) ~ 1e-17

typedef __attribute__((ext_vector_type(8))) short bf8;   // 8 bf16 (4 VGPRs)
typedef __attribute__((ext_vector_type(4))) float f4;
typedef __attribute__((ext_vector_type(2))) float f2;

__device__ __forceinline__ unsigned short f2bf(float v) {
    unsigned u = __float_as_uint(v);
    u = (u + 0x7fff + ((u >> 16) & 1)) >> 16;   // round-to-nearest-even
    return (unsigned short)u;
}

// ---------------- mega1: {edge partition} ⊕ {embedding GEMM} ⊕ {wt_c prep} ⊕ {BN const prep} ----------------
// bins: 256-node windows (bin = dst>>8); requires N <= 65536 (also for src<<8 packing and ushort buckets).
__global__ __launch_bounds__(256) void k_mega1(
        const int* __restrict__ src, const int* __restrict__ dst, int E,
        int* __restrict__ cellcnt, int* __restrict__ binbuf,
        const float* __restrict__ x, const float* __restrict__ W_emb,
        const float* __restrict__ b_emb, short* __restrict__ hbuf, int N,
        const float* __restrict__ convW, short* __restrict__ wt_c, int L,
        const float* __restrict__ convB,
        const float* __restrict__ bn_g, const float* __restrict__ bn_b,
        const float* __restrict__ bn_m, const float* __restrict__ bn_v,
        float* __restrict__ scb, float* __restrict__ shb,
        int NBIN, int EB, int WB) {
    __shared__ short wt[128 * 88];           // emb: padded W_emb^T (bank-conflict-free)
    __shared__ int lcur[256];
    const int bid = blockIdx.x;
    const int tid = threadIdx.x;

    if (bid < PB) {
        // ---- partition: LDS cursors only, private per-(block,bin) segments, packed payload ----
        lcur[tid] = 0;
        __syncthreads();
        const int per = (E + PB - 1) / PB;
        const int e0 = bid * per;
        const int e1 = (e0 + per < E) ? e0 + per : E;
        for (int e = e0 + tid; e < e1; e += 256) {
            const int d = dst[e];
            const int b = d >> 8;
            const int p = atomicAdd(&lcur[b], 1);
            if (p < SEG)
                binbuf[((size_t)b * PB + bid) * SEG + p] = (src[e] << 8) | (d & 255);
        }
        __syncthreads();
        if (tid < NBIN) {
            int c = lcur[tid];
            cellcnt[(size_t)tid * PB + bid] = c < SEG ? c : SEG;
        }
        return;
    }
    if (bid < PB + EB) {
        // ---- embedding GEMM: h = x@W_emb + b_emb, W_emb^T staged in LDS ----
        for (int i = tid; i < 128 * 64; i += 256) {
            const int n = i >> 6, k = i & 63;
            wt[n * 88 + k] = (short)f2bf(W_emb[(size_t)k * HF + n]);
        }
        __syncthreads();
        const int wid = tid >> 6, lane = tid & 63;
        const int lr = lane & 15, lk = lane >> 4;
        const int m0 = (bid - PB) * 64 + wid * 16;
        if (m0 >= N) return;
        const int arow_i = m0 + lr < N ? m0 + lr : N - 1;
        bf8 a[2];
        const float* arow = x + (size_t)arow_i * 64 + lk * 8;
#pragma unroll
        for (int kk = 0; kk < 2; ++kk) {
            const float4 p = *reinterpret_cast<const float4*>(arow + kk * 32);
            const float4 q = *reinterpret_cast<const float4*>(arow + kk * 32 + 4);
            bf8 t;
            t[0] = (short)f2bf(p.x); t[1] = (short)f2bf(p.y);
            t[2] = (short)f2bf(p.z); t[3] = (short)f2bf(p.w);
            t[4] = (short)f2bf(q.x); t[5] = (short)f2bf(q.y);
            t[6] = (short)f2bf(q.z); t[7] = (short)f2bf(q.w);
            a[kk] = t;
        }
#pragma unroll
        for (int n = 0; n < 8; ++n) {
            f4 acc = {0.f, 0.f, 0.f, 0.f};
            const short* brow = wt + (n * 16 + lr) * 88 + lk * 8;
#pragma unroll
            for (int kk = 0; kk < 2; ++kk) {
                const bf8 b = *reinterpret_cast<const bf8*>(brow + kk * 32);
                acc = __builtin_amdgcn_mfma_f32_16x16x32_bf16(a[kk], b, acc, 0, 0, 0);
            }
            const int col = n * 16 + lr;
            const float bs = b_emb[col];
#pragma unroll
            for (int r = 0; r < 4; ++r)
                hbuf[(size_t)(m0 + lk * 4 + r) * HF + col] = (short)f2bf(acc[r] + bs);
        }
        return;
    }
    if (bid < PB + EB + WB) {
        // ---- wt_c prep: wt_c[l][n][k] = bf16(convW[l][k][n]) ----
        const int i = (bid - PB - EB) * 256 + tid;
        const int per = HF * HF;
        if (i < L * per) {
            const int l = i / per, r = i % per;
            const int n = r / HF, k = r % HF;
            wt_c[i] = (short)f2bf(convW[(size_t)l * per + (size_t)k * HF + n]);
        }
        return;
    }
    // ---- BN constants: sc = rsqrt(var+eps)*gamma; sh = (convB-mean)*sc + beta ----
    const int i = (bid - PB - EB - WB) * 256 + tid;
    if (i < L * HF) {
        const float s = rsqrtf(bn_v[i] + 1e-5f) * bn_g[i];
        scb[i] = s;
        shb[i] = (convB[i] - bn_m[i]) * s + bn_b[i];
    }
}

// ---------------- binfill: L2-local bucket scatter (ushort row indices) + padding ----------------
__global__ __launch_bounds__(256) void k_binfill(
        const int* __restrict__ cellcnt, const int* __restrict__ binbuf,
        unsigned short* __restrict__ bkt, int* __restrict__ cnt,
        float* __restrict__ gbuf, short* __restrict__ mzero,
        int NBIN, int ZRIDX) {
    const int bid = blockIdx.x;
    const int tid = threadIdx.x;
    if (bid >= NBIN) {               // tail block: zero pooling accumulator + zero ms row
        for (int i = tid; i < 64 * HF; i += 256) gbuf[i] = 0.0f;
        if (tid < 64) reinterpret_cast<int*>(mzero)[tid] = 0;
        return;
    }
    __shared__ int lcnt[256];
    lcnt[tid] = 0;
    __syncthreads();
    for (int sg = tid; sg < PB; sg += 256) {
        const int c = cellcnt[(size_t)bid * PB + sg];
        const int* segp = binbuf + ((size_t)bid * PB + sg) * SEG;
        for (int i = 0; i < c; ++i) {
            const int ed = segp[i];
            const int dl = ed & 255;
            const int p = atomicAdd(&lcnt[dl], 1);
            if (p < BK)
                bkt[(size_t)((bid << 8) + dl) * BK + p] =
                    (unsigned short)((unsigned)ed >> 8);   // src row index
        }
    }
    __syncthreads();
    int c = lcnt[tid];
    if (c > BK) c = BK;
    const int pc = (c + 7) & ~7;                 // pad to multiple of 8 (<= BK)
    const int node = (bid << 8) + tid;
    unsigned short* brow = bkt + (size_t)node * BK;
    for (int p = c; p < pc; ++p) brow[p] = (unsigned short)ZRIDX;
    cnt[node] = c;
}

// ---------------- MFMA conv GEMM: C = dinv * (A @ B), 32 rows/wave ----------------
__global__ __launch_bounds__(256) void k_gemm_conv(
        const short* __restrict__ A,   // [N][128] bf16
        const short* __restrict__ Bt,  // [128][128] bf16
        const int* __restrict__ cnt,   // in-degree per node
        short* __restrict__ C,         // [N][128] bf16
        int N) {
    const int tid = threadIdx.x;
    const int wid = tid >> 6, lane = tid & 63;
    const int lr = lane & 15, lk = lane >> 4;
    const int m0 = blockIdx.x * 128 + wid * 32;
    if (m0 >= N) return;
    bf8 aA[4], aB[4];
    const short* arowA = A + (size_t)(m0 + lr) * HF + lk * 8;
    const short* arowB = arowA + 16 * HF;
#pragma unroll
    for (int kk = 0; kk < 4; ++kk) {
        aA[kk] = *reinterpret_cast<const bf8*>(arowA + kk * 32);
        aB[kk] = *reinterpret_cast<const bf8*>(arowB + kk * 32);
    }
    float dvA[4], dvB[4];
#pragma unroll
    for (int r = 0; r < 4; ++r) {
        int rowA = m0 + lk * 4 + r;       if (rowA >= N) rowA = N - 1;
        int rowB = m0 + 16 + lk * 4 + r;  if (rowB >= N) rowB = N - 1;
        dvA[r] = rsqrtf((float)cnt[rowA] + 1.0f);
        dvB[r] = rsqrtf((float)cnt[rowB] + 1.0f);
    }
#pragma unroll
    for (int n = 0; n < 8; ++n) {
        f4 accA = {0.f, 0.f, 0.f, 0.f};
        f4 accB = {0.f, 0.f, 0.f, 0.f};
        const short* brow = Bt + (size_t)(n * 16 + lr) * HF + lk * 8;
#pragma unroll
        for (int kk = 0; kk < 4; ++kk) {
            const bf8 b = *reinterpret_cast<const bf8*>(brow + kk * 32);
            accA = __builtin_amdgcn_mfma_f32_16x16x32_bf16(aA[kk], b, accA, 0, 0, 0);
            accB = __builtin_amdgcn_mfma_f32_16x16x32_bf16(aB[kk], b, accB, 0, 0, 0);
        }
        const int col = n * 16 + lr;
#pragma unroll
        for (int r = 0; r < 4; ++r) {
            C[(size_t)(m0 + lk * 4 + r) * HF + col]      = (short)f2bf(accA[r] * dvA[r]);
            C[(size_t)(m0 + 16 + lk * 4 + r) * HF + col] = (short)f2bf(accB[r] * dvB[r]);
        }
    }
}

// ---------------- fused gather + BN + LeakyReLU (ushort buckets, unroll-2, hoisted BN) ----------------
__global__ __launch_bounds__(256) void k_gather(
        const unsigned short* __restrict__ bkt, const int* __restrict__ cnt,
        const short* __restrict__ ms,
        const float* __restrict__ sc, const float* __restrict__ sh,
        short* __restrict__ h, int N) {
    const int wid  = (blockIdx.x * 256 + threadIdx.x) >> 6;
    const int lane = threadIdx.x & 63;
    const int sub  = lane >> 4;      // edge slot group 0..3
    const int lf   = lane & 15;      // feature group: 8 bf16 at offset lf*8
    if (wid >= N) return;
    const size_t b0 = (size_t)wid * BK;
    const int myoff = ((int)bkt[b0 + lane]) << 8;   // byte offset (zero-row padded)
    const int deg = cnt[wid];
    const int pdeg = (deg + 7) & ~7;

    f2 acc[4];
#pragma unroll
    for (int j = 0; j < 4; ++j) acc[j] = (f2){0.f, 0.f};
    union U { bf8 v; unsigned u[4]; };

    U self;
    self.v = *reinterpret_cast<const bf8*>(ms + (size_t)wid * HF + lf * 8);

    const char* msb = (const char*)ms + lf * 16;
    for (int t = sub; t < pdeg; t += 8) {
        const int o0 = __shfl(myoff, t);
        const int o1 = __shfl(myoff, t + 4);
        U a, b;
        a.v = *reinterpret_cast<const bf8*>(msb + o0);
        b.v = *reinterpret_cast<const bf8*>(msb + o1);
#pragma unroll
        for (int j = 0; j < 4; ++j) {
            f2 va, vb;
            va.x = __uint_as_float(a.u[j] << 16);
            va.y = __uint_as_float(a.u[j] & 0xffff0000u);
            vb.x = __uint_as_float(b.u[j] << 16);
            vb.y = __uint_as_float(b.u[j] & 0xffff0000u);
            acc[j] += va + vb;
        }
    }
    if (sub == 0) {
#pragma unroll
        for (int j = 0; j < 4; ++j) {
            f2 val;
            val.x = __uint_as_float(self.u[j] << 16);
            val.y = __uint_as_float(self.u[j] & 0xffff0000u);
            acc[j] += val;
        }
    }
#pragma unroll
    for (int j = 0; j < 4; ++j) {
        acc[j].x += __shfl_xor(acc[j].x, 16);
        acc[j].y += __shfl_xor(acc[j].y, 16);
        acc[j].x += __shfl_xor(acc[j].x, 32);
        acc[j].y += __shfl_xor(acc[j].y, 32);
    }
    if (sub == 0) {
        const float dv = rsqrtf((float)deg + 1.0f);
        const int f0 = lf * 8;
        const float4 sca = *reinterpret_cast<const float4*>(sc + f0);
        const float4 scb2 = *reinterpret_cast<const float4*>(sc + f0 + 4);
        const float4 sha = *reinterpret_cast<const float4*>(sh + f0);
        const float4 shb2 = *reinterpret_cast<const float4*>(sh + f0 + 4);
        const float scv[8] = {sca.x, sca.y, sca.z, sca.w, scb2.x, scb2.y, scb2.z, scb2.w};
        const float shv[8] = {sha.x, sha.y, sha.z, sha.w, shb2.x, shb2.y, shb2.z, shb2.w};
        unsigned ou[4];
#pragma unroll
        for (int j = 0; j < 4; ++j) {
            float vx = fmaf(acc[j].x * dv, scv[2 * j],     shv[2 * j]);
            float vy = fmaf(acc[j].y * dv, scv[2 * j + 1], shv[2 * j + 1]);
            vx = fmaxf(vx, NEG * vx);
            vy = fmaxf(vy, NEG * vy);
            ou[j] = (unsigned)f2bf(vx) | ((unsigned)f2bf(vy) << 16);
        }
        *reinterpret_cast<uint4*>(h + (size_t)wid * HF + f0) =
            *reinterpret_cast<uint4*>(ou);
    }
}

// ---------------- wave-parallel pooling with segmented register accumulation ----------------
__global__ __launch_bounds__(256) void k_pool(
        const short* __restrict__ h, const int* __restrict__ batch,
        float* __restrict__ g, int N, int per) {
    const int gwid = (blockIdx.x * 256 + threadIdx.x) >> 6;
    const int lane = threadIdx.x & 63;
    const int n0 = gwid * per;
    if (n0 >= N) return;
    const int n1 = (n0 + per < N) ? n0 + per : N;
    const int fp = lane * 2;
    float ax = 0.f, ay = 0.f;
    int cur = batch[n0];
    for (int n = n0; n < n1; ++n) {
        const int b = batch[n];
        if (b != cur) {
            atomicAdd(&g[cur * HF + fp], ax);
            atomicAdd(&g[cur * HF + fp + 1], ay);
            ax = 0.f; ay = 0.f; cur = b;
        }
        const unsigned u = *reinterpret_cast<const unsigned*>(h + (size_t)n * HF + fp);
        ax += __uint_as_float(u << 16);
        ay += __uint_as_float(u & 0xffff0000u);
    }
    atomicAdd(&g[cur * HF + fp], ax);
    atomicAdd(&g[cur * HF + fp + 1], ay);
}

// ---------------- final MLP ----------------
__global__ __launch_bounds__(128) void k_mlp(
        const float* __restrict__ g, const float* __restrict__ W1,
        const float* __restrict__ b1, const float* __restrict__ W2,
        const float* __restrict__ b2, float* __restrict__ out) {
    __shared__ float gr[128];
    __shared__ float z[64];
    const int gid = blockIdx.x, t = threadIdx.x;
    gr[t] = g[gid * HF + t];
    __syncthreads();
    if (t < 64) {
        float acc = b1[t];
#pragma unroll 8
        for (int k = 0; k < 128; ++k) acc += gr[k] * W1[k * 64 + t];
        z[t] = acc > 0.0f ? acc : NEG * acc;
    }
    __syncthreads();
    if (t < 8) {
        float acc = b2[t];
#pragma unroll 8
        for (int j = 0; j < 64; ++j) acc += z[j] * W2[j * 8 + t];
        out[gid * 8 + t] = acc;
    }
}

extern "C" void kernel_launch(void* const* d_in, const int* in_sizes, int n_in,
                              void* d_out, int out_size, void* d_ws, size_t ws_size,
                              hipStream_t stream) {
    const float* x       = (const float*)d_in[0];
    const int*   eidx    = (const int*)  d_in[1];
    const int*   batch   = (const int*)  d_in[2];
    const float* W_emb   = (const float*)d_in[3];
    const float* b_emb   = (const float*)d_in[4];
    const float* convW   = (const float*)d_in[5];
    const float* convB   = (const float*)d_in[6];
    const float* bn_g    = (const float*)d_in[7];
    const float* bn_b    = (const float*)d_in[8];
    const float* bn_m    = (const float*)d_in[9];
    const float* bn_v    = (const float*)d_in[10];
    const float* W1      = (const float*)d_in[11];
    const float* b1      = (const float*)d_in[12];
    const float* W2      = (const float*)d_in[13];
    const float* b2      = (const float*)d_in[14];

    const int F_IN = 64;
    const int N = in_sizes[0] / F_IN;
    const int E = in_sizes[1] / 2;
    const int L = in_sizes[5] / (HF * HF);
    const int G = 64;

    const int* esrc = eidx;
    const int* edst = eidx + E;

    const int NBIN  = (N + 255) >> 8;            // 256-node windows (requires N <= 65536)
    const int Npad2 = NBIN << 8;                 // bucket/cnt row count
    const int Npad  = ((N + 127) / 128) * 128;

    // workspace layout (16B alignment maintained)
    unsigned short* bkt = (unsigned short*)d_ws;             // Npad2*BK ushort
    int* cnt      = (int*)(bkt + (size_t)Npad2 * BK);        // Npad2
    int* cellcnt  = cnt + Npad2;                             // NBIN*PB
    int* binbuf   = cellcnt + (size_t)NBIN * PB;             // NBIN*PB*SEG ints (packed)
    short* hbuf   = (short*)(binbuf + (size_t)NBIN * PB * SEG); // Npad*HF bf16
    short* ms     = hbuf + (size_t)Npad * HF;                // (Npad+128)*HF bf16 (+zero row)
    short* wt_c   = ms + (size_t)(Npad + 128) * HF;          // L*128*128 bf16
    float* gbuf   = (float*)(wt_c + (size_t)L * HF * HF);    // G*HF fp32
    float* scb    = gbuf + G * HF;                           // L*HF
    float* shb    = scb + L * HF;                            // L*HF

    const int ZRIDX = Npad;                      // row index of the zero row in ms

    // 1. mega1: edge partition ⊕ embedding GEMM ⊕ wt_c prep ⊕ BN const prep
    const int EB = (N + 63) / 64;
    const int WB = (L * HF * HF + 255) / 256;
    const int SB = (L * HF + 255) / 256;
    k_mega1<<<PB + EB + WB + SB, 256, 0, stream>>>(
        esrc, edst, E, cellcnt, binbuf, x, W_emb, b_emb, hbuf, N,
        convW, wt_c, L, convB, bn_g, bn_b, bn_m, bn_v, scb, shb,
        NBIN, EB, WB);

    // 2. binfill: L2-local bucket scatter (ushort indices) + gbuf/zero-row init
    k_binfill<<<NBIN + 1, 256, 0, stream>>>(
        cellcnt, binbuf, bkt, cnt, gbuf, ms + (size_t)Npad * HF, NBIN, ZRIDX);

    // 3. conv layers
    for (int i = 0; i < L; ++i) {
        k_gemm_conv<<<(N + 127) / 128, 256, 0, stream>>>(
            hbuf, wt_c + (size_t)i * HF * HF, cnt, ms, N);
        k_gather<<<(N * 64 + 255) / 256, 256, 0, stream>>>(
            bkt, cnt, ms, scb + i * HF, shb + i * HF, hbuf, N);
    }

    // 4. pooling (wave-parallel, segmented; 2048 waves) + MLP
    const int nwaves = 512 * 4;
    const int per = (N + nwaves - 1) / nwaves;
    k_pool<<<512, 256, 0, stream>>>(hbuf, batch, gbuf, N, per);
    k_mlp<<<G, 128, 0, stream>>>(gbuf, W1, b1, W2, b2, (float*)d_out);
}